// Round 9
// baseline (342.212 us; speedup 1.0000x reference)
//
#include <hip/hip_runtime.h>
#include <hip/hip_fp16.h>

#define B_  32
#define L_  2048
#define H_  512
#define CA  64        // chunk size; 32 serial steps per batch
#define NC  32        // chunks per batch; key row l=2047 zero-padded
#define EPSF 1e-6f

typedef _Float16 f16x8 __attribute__((ext_vector_type(8)));
typedef float f32x16 __attribute__((ext_vector_type(16)));

// ---- wave64 sum reduction via DPP; full sum lands in lane 63 ----
template <int CTRL>
__device__ __forceinline__ float dpp_shift_add(float x) {
  int t = __builtin_amdgcn_update_dpp(0, __float_as_int(x), CTRL, 0xf, 0xf, true);
  return x + __int_as_float(t);
}
__device__ __forceinline__ float wave_reduce_lane63(float x) {
  x = dpp_shift_add<0x111>(x);  // row_shr:1
  x = dpp_shift_add<0x112>(x);  // row_shr:2
  x = dpp_shift_add<0x114>(x);  // row_shr:4
  x = dpp_shift_add<0x118>(x);  // row_shr:8
  x = dpp_shift_add<0x142>(x);  // row_bcast:15
  x = dpp_shift_add<0x143>(x);  // row_bcast:31
  return x;                     // valid in lane 63
}
// sum within each 16-lane DPP row; result valid in lane 15 of each row
__device__ __forceinline__ float row16_reduce(float x) {
  x = dpp_shift_add<0x111>(x);
  x = dpp_shift_add<0x112>(x);
  x = dpp_shift_add<0x114>(x);
  x = dpp_shift_add<0x118>(x);
  return x;
}
__device__ __forceinline__ float rdlane(float v, int l) {
  return __int_as_float(__builtin_amdgcn_readlane(__float_as_int(v), l));
}
__device__ __forceinline__ __half2 u2h2(unsigned int u) {
  __half2 h; *(unsigned int*)&h = u; return h;
}
__device__ __forceinline__ unsigned int h22u(__half2 h) {
  return *(unsigned int*)&h;
}
// pack two float4s (8 consecutive key elems) into 4 fp16x2 words (RNE,
// bit-identical to gram's __floats2half2_rn rounding)
__device__ __forceinline__ uint4 pack8_rn(const float4& a, const float4& b) {
  return make_uint4(h22u(__floats2half2_rn(a.x, a.y)),
                    h22u(__floats2half2_rn(a.z, a.w)),
                    h22u(__floats2half2_rn(b.x, b.y)),
                    h22u(__floats2half2_rn(b.z, b.w)));
}

// Kf LDS layout: row-major 16B granules, XOR-swizzled. u16 index:
#define KFI(row, k8) (((((row) * 64) + (k8)) * 8) ^ (((row) & 7) << 3))

// =====================================================================
// Kernel A: Gram via MFMA + X = (D + triu(G,1))^{-1} via reg backsubs +
// Schur. NO Kh output (scan re-reads hidden directly). 256 thr, 80 KiB.
// =====================================================================
__global__ __launch_bounds__(256) void
deltarule_gram64(const float* __restrict__ hidden,
                 float* __restrict__ tmT, float* __restrict__ dvec) {
  const int cb = blockIdx.x, b = blockIdx.y;
  const int tid = threadIdx.x, lane = tid & 63, wv = tid >> 6;
  __shared__ __align__(16) unsigned short Kf[CA * H_];  // 64 KB fp16, swizzled granules
  __shared__ __align__(16) float G[CA * CA];            // 16 KB

  const int c0 = cb * CA;
  const float* src = hidden + ((size_t)b * L_ + c0) * H_;
  const bool lastc = (cb == NC - 1);

  // ---- stage + round to fp16 (LDS only) ----
#pragma unroll
  for (int u = 0; u < 16; ++u) {
    const int f8 = u * 256 + tid;
    const int row = f8 >> 6;
    const int colf = (f8 & 63) * 8;
    float4 va = *(const float4*)(src + row * H_ + colf);
    float4 vb = *(const float4*)(src + row * H_ + colf + 4);
    if (lastc && row == CA - 1) {   // zero-pad key row l=2047
      va = make_float4(0.f, 0.f, 0.f, 0.f);
      vb = make_float4(0.f, 0.f, 0.f, 0.f);
    }
    const uint4 pk = pack8_rn(va, vb);
    *(uint4*)&Kf[KFI(row, colf >> 3)] = pk;
  }
  __syncthreads();

  // ---- Gram via MFMA: waves 0,1,2 -> tiles (0,0),(0,1),(1,1) ----
  if (wv < 3) {
    const int ta = (wv == 2) ? 1 : 0;
    const int tb = (wv == 0) ? 0 : 1;
    const int mrow = 32 * ta + (lane & 31);
    const int nrow = 32 * tb + (lane & 31);
    const int khi = lane >> 5;
    f32x16 acc;
#pragma unroll
    for (int r = 0; r < 16; ++r) acc[r] = 0.f;
#pragma unroll
    for (int kk = 0; kk < 32; ++kk) {
      const int k8 = 2 * kk + khi;
      const f16x8 av = *(const f16x8*)&Kf[KFI(mrow, k8)];
      const f16x8 bv = *(const f16x8*)&Kf[KFI(nrow, k8)];
      acc = __builtin_amdgcn_mfma_f32_32x32x16_f16(av, bv, acc, 0, 0, 0);
    }
#pragma unroll
    for (int r = 0; r < 16; ++r) {
      const int row32 = (r & 3) + 8 * (r >> 2) + 4 * khi;
      G[(32 * ta + row32) * CA + 32 * tb + (lane & 31)] = acc[r];
    }
  }
  __syncthreads();

  // ---- dvec = diag(G)+eps ----
  if (tid < CA) dvec[((size_t)b * NC + cb) * CA + tid] = G[tid * CA + tid] + EPSF;
  __syncthreads();

  // ---- two parallel 32x32 backsubs (regs + readlane) ----
  if (wv < 2) {
    const int off = wv * 32;          // wave0 -> X00, wave1 -> X11
    const int j = lane & 31;
    float Gr[32], X[32];
#pragma unroll
    for (int t = 0; t < 32; ++t) Gr[t] = G[(off + t) * CA + off + j];
#pragma unroll
    for (int t = 31; t >= 0; --t) {
      float i0 = 0.f, i1 = 0.f;
#pragma unroll
      for (int s = t + 1; s < 32; s += 2) i0 = fmaf(rdlane(Gr[t], s), X[s], i0);
#pragma unroll
      for (int s = t + 2; s < 32; s += 2) i1 = fmaf(rdlane(Gr[t], s), X[s], i1);
      X[t] = (((j == t) ? 1.f : 0.f) - (i0 + i1)) / (rdlane(Gr[t], t) + EPSF);
    }
    if (lane < 32) {
#pragma unroll
      for (int t = 0; t < 32; ++t) G[(off + t) * CA + off + j] = X[t];
    }
  }
  __syncthreads();

  // ---- Schur: Z = U12 * X11, then Y = -X00 * Z over the U12 slot ----
  const int zr = tid >> 3;
  const int zc = (tid & 7) * 4;
  float4 zf = make_float4(0.f, 0.f, 0.f, 0.f);
#pragma unroll
  for (int s = 0; s < 32; ++s) {
    const float u = G[zr * CA + 32 + s];
    const float4 xv = *(const float4*)&G[(32 + s) * CA + 32 + zc];
    zf.x = fmaf(u, xv.x, zf.x); zf.y = fmaf(u, xv.y, zf.y);
    zf.z = fmaf(u, xv.z, zf.z); zf.w = fmaf(u, xv.w, zf.w);
  }
  __syncthreads();
  *(float4*)&G[zr * CA + 32 + zc] = zf;
  __syncthreads();
  float4 yf = make_float4(0.f, 0.f, 0.f, 0.f);
#pragma unroll
  for (int s = 0; s < 32; ++s) {
    const float u = G[zr * CA + s];
    const float4 zv = *(const float4*)&G[s * CA + 32 + zc];
    yf.x = fmaf(u, zv.x, yf.x); yf.y = fmaf(u, zv.y, yf.y);
    yf.z = fmaf(u, zv.z, yf.z); yf.w = fmaf(u, zv.w, yf.w);
  }
  __syncthreads();
  *(float4*)&G[zr * CA + 32 + zc] = make_float4(-yf.x, -yf.y, -yf.z, -yf.w);
  __syncthreads();

  // ---- write tmT (fp32) flat[s*64+j] = X[s][j]; lower-left block = 0 ----
  float* tout = tmT + ((size_t)b * NC + cb) * (CA * CA);
#pragma unroll
  for (int v = 0; v < 4; ++v) {
    const int f4 = v * 256 + tid;
    const int s = f4 >> 4;
    const int j4 = (f4 & 15) * 4;
    float4 val;
    if (s >= 32 && j4 < 32) val = make_float4(0.f, 0.f, 0.f, 0.f);
    else                    val = *(const float4*)&G[s * CA + j4];
    *(float4*)(tout + s * CA + j4) = val;
  }
}

// =====================================================================
// Kernel B v9: packed-fp16 register scan reading fp32 keys directly from
// hidden (no Kh workspace). 1024 threads (16 waves). Wave wv owns key
// rows 4wv..4wv+3; fp32 prefetch -> RNE-pack to fp16 at rotate (bit-
// identical to gram's rounding). Structure otherwise = round-7 v8:
// fp16 w in LDS + f32 master in waves 0-3; hfma2 dot/update; padded f32
// sigma partials + DPP; packed-fp16 PartU combine (waves 0-3 w, 4-7 ctx).
// 3 barriers/step.
// =====================================================================
__global__ __launch_bounds__(1024) void
deltarule_scan16(const float* __restrict__ hidden,
                 const float* __restrict__ Wm, const float* __restrict__ bias,
                 const float* __restrict__ tmT, const float* __restrict__ dvec,
                 float* __restrict__ out) {
  const int b = blockIdx.x, tid = threadIdx.x, lane = tid & 63, wv = tid >> 6;
  __shared__ __align__(16) unsigned int PartU16[16][512]; // 32 KB: [256 w-words | 256 c-words]
  __shared__ __align__(16) unsigned int Wsw16[256];       // packed fp16 w (plain order)
  __shared__ __align__(16) float Ctx[H_];                 // f32 ctx (epilogue)
  __shared__ float Part2[64 * 17];                        // f32 sigma partials (padded)

  const float* hb  = hidden + (size_t)b * L_ * H_;
  const float* tmb = tmT + (size_t)b * NC * (CA * CA);
  const float* dvb = dvec + (size_t)b * NC * CA;

  const int t256 = 64 * (wv & 3) + lane;   // 0..255 within each 4-wave group

  // ---- init: pack q into Wsw16; f32 master in waves 0-3 ----
  if (tid < 256) {
    const float2 q = *(const float2*)(hb + (size_t)(L_ - 1) * H_ + 2 * tid);
    Wsw16[tid] = h22u(__floats2half2_rn(q.x, q.y));
  }
  float wq0 = 0.f, wq1 = 0.f, cx0 = 0.f, cx1 = 0.f;
  if (wv < 4) {
    const float2 q = *(const float2*)(hb + (size_t)(L_ - 1) * H_ + 2 * t256);
    wq0 = q.x; wq1 = q.y;
  }

  // ---- preloop: prefetch chunk NC-1 fp32 rows / X slice / d ----
  uint4 kr[4];
  float4 tA;
  float dv;
  {
    float4 kf0[4], kf1[4];
#pragma unroll
    for (int i = 0; i < 4; ++i) {
      const float* rp = hb + ((size_t)(NC - 1) * CA + 4 * wv + i) * H_ + 8 * lane;
      kf0[i] = *(const float4*)rp;
      kf1[i] = *(const float4*)(rp + 4);
    }
    if (wv == 15) {   // key row l=2047 is padding -> zero
      kf0[3] = make_float4(0.f, 0.f, 0.f, 0.f);
      kf1[3] = make_float4(0.f, 0.f, 0.f, 0.f);
    }
#pragma unroll
    for (int i = 0; i < 4; ++i) kr[i] = pack8_rn(kf0[i], kf1[i]);
  }
  tA = *(const float4*)(tmb + (size_t)(NC - 1) * (CA * CA) + lane * CA + 4 * wv);
  dv = dvb[(NC - 1) * CA + lane];
  asm volatile("s_waitcnt vmcnt(0) lgkmcnt(0)\n\ts_barrier" ::: "memory");

  for (int c = NC - 1; c >= 0; --c) {
    // ---- prefetch chunk c-1 (fp32 global; packed at rotate) ----
    float4 kn0[4], kn1[4];
    float4 nA;
    float dN = 0.f;
    if (c > 0) {
#pragma unroll
      for (int i = 0; i < 4; ++i) {
        const float* rp = hb + ((size_t)(c - 1) * CA + 4 * wv + i) * H_ + 8 * lane;
        kn0[i] = *(const float4*)rp;
        kn1[i] = *(const float4*)(rp + 4);
      }
      nA = *(const float4*)(tmb + (size_t)(c - 1) * (CA * CA) + lane * CA + 4 * wv);
      dN = dvb[(c - 1) * CA + lane];
    }

    // ---- dot: y[4wv+i] = K~[row].w via packed fp16 fma ----
    const uint4 wv4 = *(const uint4*)&Wsw16[4 * lane];
    float ysg[4];
#pragma unroll
    for (int i = 0; i < 4; ++i) {
      __half2 acc = __hmul2(u2h2(kr[i].x), u2h2(wv4.x));
      acc = __hfma2(u2h2(kr[i].y), u2h2(wv4.y), acc);
      acc = __hfma2(u2h2(kr[i].z), u2h2(wv4.z), acc);
      acc = __hfma2(u2h2(kr[i].w), u2h2(wv4.w), acc);
      const float2 pf = __half22float2(acc);
      float p = pf.x + pf.y;
      p = wave_reduce_lane63(p);
      ysg[i] = rdlane(p, 63);
    }

    // ---- sigma partial: sp[j=lane] = sum_i y[4wv+i] * X[j][4wv+i] ----
    float sp = ysg[0] * tA.x;
    sp = fmaf(ysg[1], tA.y, sp);
    sp = fmaf(ysg[2], tA.z, sp);
    sp = fmaf(ysg[3], tA.w, sp);
    Part2[lane * 17 + wv] = sp;
    asm volatile("s_waitcnt lgkmcnt(0)\n\ts_barrier" ::: "memory");  // b1

    // ---- sigma for this wave's 4 rows: 1 read + DPP row16 + readlane ----
    float red = Part2[(4 * wv + (lane >> 4)) * 17 + (lane & 15)];
    red = row16_reduce(red);
    const float sg0 = rdlane(red, 15);
    const float sg1 = rdlane(red, 31);
    const float sg2 = rdlane(red, 47);
    const float sg3 = rdlane(red, 63);
    const float sv0 = sg0 * rdlane(dv, 4 * wv + 0);
    const float sv1 = sg1 * rdlane(dv, 4 * wv + 1);
    const float sv2 = sg2 * rdlane(dv, 4 * wv + 2);
    const float sv3 = sg3 * rdlane(dv, 4 * wv + 3);

    // ---- update partials in packed fp16 (lane owns h = 8*lane..8*lane+7) ----
    {
      const __half2 g0 = __float2half2_rn(sg0), g1 = __float2half2_rn(sg1);
      const __half2 g2 = __float2half2_rn(sg2), g3 = __float2half2_rn(sg3);
      const __half2 v0 = __float2half2_rn(sv0), v1 = __float2half2_rn(sv1);
      const __half2 v2 = __float2half2_rn(sv2), v3 = __float2half2_rn(sv3);
      uint4 wsu, csu;
      {
        __half2 a, bqq;
        // word x
        a = __hmul2(g0, u2h2(kr[0].x)); a = __hfma2(g1, u2h2(kr[1].x), a);
        a = __hfma2(g2, u2h2(kr[2].x), a); a = __hfma2(g3, u2h2(kr[3].x), a);
        wsu.x = h22u(a);
        bqq = __hmul2(v0, u2h2(kr[0].x)); bqq = __hfma2(v1, u2h2(kr[1].x), bqq);
        bqq = __hfma2(v2, u2h2(kr[2].x), bqq); bqq = __hfma2(v3, u2h2(kr[3].x), bqq);
        csu.x = h22u(bqq);
        // word y
        a = __hmul2(g0, u2h2(kr[0].y)); a = __hfma2(g1, u2h2(kr[1].y), a);
        a = __hfma2(g2, u2h2(kr[2].y), a); a = __hfma2(g3, u2h2(kr[3].y), a);
        wsu.y = h22u(a);
        bqq = __hmul2(v0, u2h2(kr[0].y)); bqq = __hfma2(v1, u2h2(kr[1].y), bqq);
        bqq = __hfma2(v2, u2h2(kr[2].y), bqq); bqq = __hfma2(v3, u2h2(kr[3].y), bqq);
        csu.y = h22u(bqq);
        // word z
        a = __hmul2(g0, u2h2(kr[0].z)); a = __hfma2(g1, u2h2(kr[1].z), a);
        a = __hfma2(g2, u2h2(kr[2].z), a); a = __hfma2(g3, u2h2(kr[3].z), a);
        wsu.z = h22u(a);
        bqq = __hmul2(v0, u2h2(kr[0].z)); bqq = __hfma2(v1, u2h2(kr[1].z), bqq);
        bqq = __hfma2(v2, u2h2(kr[2].z), bqq); bqq = __hfma2(v3, u2h2(kr[3].z), bqq);
        csu.z = h22u(bqq);
        // word w
        a = __hmul2(g0, u2h2(kr[0].w)); a = __hfma2(g1, u2h2(kr[1].w), a);
        a = __hfma2(g2, u2h2(kr[2].w), a); a = __hfma2(g3, u2h2(kr[3].w), a);
        wsu.w = h22u(a);
        bqq = __hmul2(v0, u2h2(kr[0].w)); bqq = __hfma2(v1, u2h2(kr[1].w), bqq);
        bqq = __hfma2(v2, u2h2(kr[2].w), bqq); bqq = __hfma2(v3, u2h2(kr[3].w), bqq);
        csu.w = h22u(bqq);
      }
      *(uint4*)&PartU16[wv][4 * lane]       = wsu;  // conflict-free b128
      *(uint4*)&PartU16[wv][256 + 4 * lane] = csu;
    }
    asm volatile("s_waitcnt lgkmcnt(0)\n\ts_barrier" ::: "memory");  // b2

    // ---- combine: conflict-free (word t across lanes is consecutive) ----
    if (wv < 4) {          // w: subtract from f32 master, publish fp16
      __half2 s = u2h2(PartU16[0][t256]);
#pragma unroll
      for (int w2 = 1; w2 < 16; ++w2) s = __hadd2(s, u2h2(PartU16[w2][t256]));
      const float2 sf = __half22float2(s);
      wq0 -= sf.x; wq1 -= sf.y;
      Wsw16[t256] = h22u(__floats2half2_rn(wq0, wq1));
    } else if (wv < 8) {   // ctx: accumulate f32 in registers
      __half2 s = u2h2(PartU16[0][256 + t256]);
#pragma unroll
      for (int w2 = 1; w2 < 16; ++w2) s = __hadd2(s, u2h2(PartU16[w2][256 + t256]));
      const float2 sf = __half22float2(s);
      cx0 += sf.x; cx1 += sf.y;
    }

    // rotate prefetched regs: RNE-pack fp32 -> fp16 (same rounding as gram)
    if (c > 0) {
      dv = dN; tA = nA;
#pragma unroll
      for (int i = 0; i < 4; ++i) kr[i] = pack8_rn(kn0[i], kn1[i]);
    }
    asm volatile("s_waitcnt vmcnt(0) lgkmcnt(0)\n\ts_barrier" ::: "memory");  // b3
  }

  // ---- epilogue: out[b] = W @ ctx + bias ----
  if (wv >= 4 && wv < 8) *(float2*)&Ctx[2 * t256] = make_float2(cx0, cx1);
  __syncthreads();
  {
    float* Ep = (float*)&PartU16[0][0];
    const int o = tid & (H_ - 1);
    const int hf = tid >> 9;
    float acc = 0.f;
    const float* wr = Wm + (size_t)o * H_ + hf * 256;
    const float* cx = &Ctx[hf * 256];
#pragma unroll 8
    for (int i = 0; i < 256; i += 4) {
      const float4 w4 = *(const float4*)(wr + i);
      const float4 cv = *(const float4*)(cx + i);
      acc = fmaf(w4.x, cv.x, acc); acc = fmaf(w4.y, cv.y, acc);
      acc = fmaf(w4.z, cv.z, acc); acc = fmaf(w4.w, cv.w, acc);
    }
    Ep[hf * 512 + o] = acc;
    __syncthreads();
    if (tid < H_) out[(size_t)b * H_ + tid] = Ep[tid] + Ep[512 + tid] + bias[tid];
  }
}

// =====================================================================
extern "C" void kernel_launch(void* const* d_in, const int* in_sizes, int n_in,
                              void* d_out, int out_size, void* d_ws, size_t ws_size,
                              hipStream_t stream) {
  (void)in_sizes; (void)n_in; (void)out_size; (void)ws_size;
  const float* hidden = (const float*)d_in[0];  // (32, 2048, 512) fp32
  const float* Wm     = (const float*)d_in[1];  // (512, 512) fp32
  const float* bias   = (const float*)d_in[2];  // (512,) fp32
  float* out = (float*)d_out;                   // (32, 512) fp32

  // workspace: tmT 16 MB (fp32) + dvec 256 KB  (no Kh: scan reads hidden)
  float* tmT  = (float*)d_ws;
  float* dvec = tmT + (size_t)B_ * NC * CA * CA;

  deltarule_gram64<<<dim3(NC, B_), 256, 0, stream>>>(hidden, tmT, dvec);
  deltarule_scan16<<<B_, 1024, 0, stream>>>(hidden, Wm, bias, tmT, dvec, out);
}